// Round 5
// baseline (296.925 us; speedup 1.0000x reference)
//
#include <hip/hip_runtime.h>
#include <math.h>

namespace {

constexpr int Himg = 224, Wimg = 224, Cn = 3, Kk = 32;
constexpr int MAXT = 64;
constexpr int WSTRIDE = 512;            // ints per image in tap workspace
constexpr int IMG_F  = Himg * Wimg * Cn;       // 150528 floats per image
// padded image: 255 rows (15 top + 224 + 16 bottom), 256-px rows (16 left pad)
constexpr int PAD_ROW_F  = 256 * Cn;           // 768 floats per padded row
constexpr int PAD_ROW_B  = PAD_ROW_F * 4;      // 3072 B
constexpr int PAD_ROWS   = 255;
constexpr int PAD_IMG_F  = PAD_ROWS * PAD_ROW_F;   // 195840
constexpr size_t TAPS_BYTES = 128 * WSTRIDE * sizeof(int);  // 256 KiB

constexpr int VQ  = 4;                  // output rows per thread
constexpr int CHW = 168;                // 16B chunks per output row (672 floats)
constexpr int THR_PER_IMG = (Himg / VQ) * CHW;   // 9408

// ws per-image layout (ints): [0]=n  [1]=w  [2..65]=dky  [66..129]=dkx
// [130..193]=voff(fallback)  [194]=R  [195..258]=run_off  [259..322]=run_len

typedef float v4  __attribute__((ext_vector_type(4), aligned(4)));
typedef float v4a __attribute__((ext_vector_type(4), aligned(16)));

// ---------------- pre-pass: tap list + vertical-run decomposition ----------------
__global__ __launch_bounds__(64)
void build_taps(const float* __restrict__ tbl,
                const int* __restrict__ amt,
                const int* __restrict__ ang,
                int* __restrict__ ws)
{
    const int b   = blockIdx.x;
    const int tid = threadIdx.x;

    __shared__ int      s_cnt;
    __shared__ float    s_w;
    __shared__ int      s_dky[MAXT], s_dkx[MAXT], s_voff[MAXT];
    __shared__ unsigned s_colmask[Kk];

    if (tid == 0) { s_cnt = 0; s_w = 0.0f; }
    if (tid < Kk) s_colmask[tid] = 0u;
    __syncthreads();

    const int a = amt[b];
    // reference-exact numerics (verified absmax 0.0039 in R1-R4)
    const float  rad = (float)ang[b] * (float)(M_PI / 180.0);
    const double rd  = (double)rad;
    const float  cth = (float)cos(rd);
    const float  sth = (float)sin(rd);
    const float  e   = 31.0f;
    const float xoff = __fmul_rn(__fsub_rn(e, __fsub_rn(__fmul_rn(cth, e), __fmul_rn(sth, e))), 0.5f);
    const float yoff = __fmul_rn(__fsub_rn(e, __fadd_rn(__fmul_rn(sth, e), __fmul_rn(cth, e))), 0.5f);

    for (int p = tid; p < Kk * Kk; p += 64) {
        const int   ky = p >> 5, kx = p & 31;
        const float xf = (float)kx, yf = (float)ky;
        const float sx = __fadd_rn(__fsub_rn(__fmul_rn(cth, xf), __fmul_rn(sth, yf)), xoff);
        const float sy = __fadd_rn(__fadd_rn(__fmul_rn(sth, xf), __fmul_rn(cth, yf)), yoff);
        const int ix = (int)rintf(sx);   // round-half-even == jnp.round
        const int iy = (int)rintf(sy);
        if (ix >= 0 && ix < Kk && iy >= 0 && iy < Kk) {
            const float v = tbl[((a * Kk + iy) * Kk + ix) * Cn];
            if (v != 0.0f) {
                const int idx = atomicAdd(&s_cnt, 1);
                if (idx < MAXT) {
                    s_dky[idx]  = ky - 15;
                    s_dkx[idx]  = kx - 15;
                    s_voff[idx] = ((ky - 15) * Wimg + (kx - 15)) * (int)(Cn * sizeof(float));
                    s_w = v;                 // benign race: all writers store 1/size
                }
                atomicOr(&s_colmask[kx], 1u << ky);
            }
        }
    }
    __syncthreads();

    const int n = min(s_cnt, MAXT);
    int* wsb = ws + b * WSTRIDE;
    if (tid == 0) { wsb[0] = n; wsb[1] = __float_as_int(s_w); }
    for (int i = tid; i < n; i += 64) {
        wsb[2 + i]   = s_dky[i];
        wsb[66 + i]  = s_dkx[i];
        wsb[130 + i] = s_voff[i];
    }

    if (tid == 0) {
        // decompose columns into maximal vertical runs
        int r = 0;
        for (int c = 0; c < Kk; ++c) {
            const unsigned m = s_colmask[c];
            int start = -1;
            for (int bit = 0; bit <= Kk; ++bit) {
                const int set = (bit < Kk) && ((m >> bit) & 1u);
                if (set && start < 0) start = bit;
                if (!set && start >= 0) {
                    const int dky = start - 15, dkx = c - 15, span = bit - start;
                    wsb[195 + r] = dky * PAD_ROW_B + dkx * (int)(Cn * sizeof(float));
                    wsb[259 + r] = span;
                    ++r;
                    start = -1;
                }
            }
        }
        wsb[194] = r;
    }
}

// ---------------- pad pass: zero-padded, 256-px-stride images ----------------
__global__ __launch_bounds__(256)
void pad_images(const float* __restrict__ x, float* __restrict__ pad)
{
    const int idx = blockIdx.x * 256 + threadIdx.x;    // < 128*48960
    const int b   = idx / (PAD_ROWS * 192);
    const int r   = idx - b * (PAD_ROWS * 192);
    const int yy  = r / 192;
    const int j   = r - yy * 192;
    const int fd0 = j << 2;
    const int ysrc = yy - 15;

    const int o  = ysrc * (Wimg * Cn) + fd0 - 48;
    const int oc = min(max(o, 0), IMG_F - 4);
    const v4a v  = *(const v4a*)(x + (size_t)b * IMG_F + oc);

    const bool ok = ((unsigned)ysrc < (unsigned)Himg) & (fd0 >= 48) & (fd0 < 720);
    const float m = ok ? 1.0f : 0.0f;

    v4a* dp = (v4a*)(pad + (size_t)b * PAD_IMG_F + (size_t)yy * PAD_ROW_F + fd0);
    *dp = v4a{v.x * m, v.y * m, v.z * m, v.w * m};
}

// ---------------- conv: 4 output rows/thread, rolling window over vertical runs ----------------
__global__ __launch_bounds__(256)
void blur_conv_v4(const float* __restrict__ pad,
                  const int* __restrict__ ws,
                  float* __restrict__ out)
{
    const int b   = blockIdx.y;
    const int tid = threadIdx.x;

    __shared__ int shRW[2];
    __shared__ int s_roff[MAXT], s_rlen[MAXT];
    const int* wsb = ws + b * WSTRIDE;
    if (tid == 0) { shRW[0] = wsb[194]; shRW[1] = wsb[1]; }
    if (tid < MAXT) { s_roff[tid] = wsb[195 + tid]; s_rlen[tid] = wsb[259 + tid]; }
    __syncthreads();

    const int   R = shRW[0];
    const float w = __int_as_float(shRW[1]);

    int idx = blockIdx.x * 256 + tid;
    const bool valid = idx < THR_PER_IMG;
    idx = valid ? idx : 0;
    const int q = idx / CHW;              // row-quad
    const int k = idx - q * CHW;          // 16B chunk within row
    const int y0 = q * VQ;

    // byte address of this thread's chunk at output row y0, padded space
    const char* base = (const char*)(pad + (size_t)b * PAD_IMG_F)
                     + (y0 + 15) * PAD_ROW_B + (k << 4) + 192;

    v4 a0 = {0,0,0,0}, a1 = {0,0,0,0}, a2 = {0,0,0,0}, a3 = {0,0,0,0};

    for (int r = 0; r < R; ++r) {                    // wave-uniform
        const char* p = base + s_roff[r];
        const int   s = s_rlen[r];
        if (s >= VQ) {
            // ramp-up (window grows)
            v4 v0 = *(const v4*)(p);                  a0 += v0;
            v4 v1 = *(const v4*)(p + PAD_ROW_B);      a0 += v1; a1 += v1;
            v4 v2 = *(const v4*)(p + 2*PAD_ROW_B);    a0 += v2; a1 += v2; a2 += v2;
            const char* pp = p + 3*PAD_ROW_B;
            // steady state: full window, branch-free
            for (int i = VQ - 1; i < s; ++i) {
                v4 v = *(const v4*)(pp); pp += PAD_ROW_B;
                a0 += v; a1 += v; a2 += v; a3 += v;
            }
            // ramp-down (window shrinks)
            v4 u0 = *(const v4*)(pp);                 a1 += u0; a2 += u0; a3 += u0;
            v4 u1 = *(const v4*)(pp + PAD_ROW_B);     a2 += u1; a3 += u1;
            v4 u2 = *(const v4*)(pp + 2*PAD_ROW_B);   a3 += u2;
        } else {
            // short runs (s = 1..3): generic windowed loop, <=6 iters, wave-uniform
            const char* pp = p;
            for (int i = 0; i < s + VQ - 1; ++i) {
                v4 v = *(const v4*)(pp); pp += PAD_ROW_B;
                if (i < s)              a0 += v;
                if (i >= 1 && i < s+1)  a1 += v;
                if (i >= 2 && i < s+2)  a2 += v;
                if (i >= 3)             a3 += v;
            }
        }
    }

    if (valid) {
        float* o = out + (size_t)b * IMG_F + (size_t)y0 * (Wimg*Cn) + (k << 2);
        *(v4a*)(o)               = v4a{a0.x*w, a0.y*w, a0.z*w, a0.w*w};
        *(v4a*)(o +   Wimg*Cn)   = v4a{a1.x*w, a1.y*w, a1.z*w, a1.w*w};
        *(v4a*)(o + 2*Wimg*Cn)   = v4a{a2.x*w, a2.y*w, a2.z*w, a2.w*w};
        *(v4a*)(o + 3*Wimg*Cn)   = v4a{a3.x*w, a3.y*w, a3.z*w, a3.w*w};
    }
}

// ---------------- fallback conv (R3, reads x directly) if ws too small ----------------
constexpr int TILE = 32;
__global__ __launch_bounds__(256)
void blur_conv(const float* __restrict__ x,
               const int* __restrict__ ws,
               float* __restrict__ out)
{
    const int b   = blockIdx.z;
    const int tid = threadIdx.x;

    __shared__ int sh[2 + 3 * MAXT];
    const int* wsb = ws + b * WSTRIDE;
    if (tid < 2 + 3 * MAXT) sh[tid] = wsb[tid];
    __syncthreads();

    const int   n = sh[0];
    const float w = __int_as_float(sh[1]);
    const int* s_dky  = sh + 2;
    const int* s_dkx  = sh + 2 + MAXT;
    const int* s_voff = sh + 2 + 2 * MAXT;

    const int x0 = blockIdx.x * TILE, y0 = blockIdx.y * TILE;
    const int tx = tid & 7, ty = tid >> 3;
    const int oy  = y0 + ty;
    const int ox0 = x0 + tx * 4;

    const float* xb = x + (size_t)b * IMG_F;

    float acc[12];
#pragma unroll
    for (int qq = 0; qq < 12; ++qq) acc[qq] = 0.0f;

    const bool border = (x0 < 15) || (x0 + TILE + 16 > Wimg) ||
                        (y0 < 15) || (y0 + TILE + 16 > Himg);

    if (!border) {
        const int base_off = (oy * Wimg + ox0) * (int)(Cn * sizeof(float));
        for (int i = 0; i < n; ++i) {
            const char* p = (const char*)xb + (base_off + s_voff[i]);
            const v4 f0 = *(const v4*)(p);
            const v4 f1 = *(const v4*)(p + 16);
            const v4 f2 = *(const v4*)(p + 32);
            acc[0] += f0.x; acc[1] += f0.y; acc[2]  += f0.z; acc[3]  += f0.w;
            acc[4] += f1.x; acc[5] += f1.y; acc[6]  += f1.z; acc[7]  += f1.w;
            acc[8] += f2.x; acc[9] += f2.y; acc[10] += f2.z; acc[11] += f2.w;
        }
    } else {
        for (int i = 0; i < n; ++i) {
            const int yy  = oy + s_dky[i];
            const int xx0 = ox0 + s_dkx[i];
            const bool rowok  = (unsigned)yy < (unsigned)Himg;
            const int rowbase = yy * Wimg;
#pragma unroll
            for (int j = 0; j < 4; ++j) {
                const int  xx = xx0 + j;
                const bool ok = rowok & ((unsigned)xx < (unsigned)Wimg);
                const int off = ok ? (rowbase + xx) * (int)(Cn * sizeof(float)) : 0;
                const float* p = (const float*)((const char*)xb + off);
                const float m  = ok ? 1.0f : 0.0f;
                acc[3 * j + 0] += m * p[0];
                acc[3 * j + 1] += m * p[1];
                acc[3 * j + 2] += m * p[2];
            }
        }
    }

    float rr[12];
#pragma unroll
    for (int qq = 0; qq < 12; ++qq) rr[qq] = acc[qq] * w;

    float* o = out + ((size_t)(b * Himg + oy) * Wimg + ox0) * Cn;
    *(v4*)(o)     = v4{rr[0], rr[1], rr[2],  rr[3]};
    *(v4*)(o + 4) = v4{rr[4], rr[5], rr[6],  rr[7]};
    *(v4*)(o + 8) = v4{rr[8], rr[9], rr[10], rr[11]};
}

}  // namespace

extern "C" void kernel_launch(void* const* d_in, const int* in_sizes, int n_in,
                              void* d_out, int out_size, void* d_ws, size_t ws_size,
                              hipStream_t stream) {
    const float* x   = (const float*)d_in[0];
    const float* tbl = (const float*)d_in[1];
    const int*   amt = (const int*)d_in[2];
    const int*   ang = (const int*)d_in[3];
    float*       out = (float*)d_out;
    int*         ws  = (int*)d_ws;

    const int B = in_sizes[2];  // 128

    build_taps<<<B, 64, 0, stream>>>(tbl, amt, ang, ws);

    const size_t need = TAPS_BYTES + (size_t)B * PAD_IMG_F * sizeof(float);
    if (ws_size >= need) {
        float* pad = (float*)((char*)d_ws + TAPS_BYTES);
        const int pad_blocks = B * PAD_ROWS * 192 / 256;            // 24480
        pad_images<<<pad_blocks, 256, 0, stream>>>(x, pad);
        dim3 grid((THR_PER_IMG + 255) / 256, B);                    // (37, 128)
        blur_conv_v4<<<grid, 256, 0, stream>>>(pad, ws, out);
    } else {
        dim3 grid(Wimg / TILE, Himg / TILE, B);
        blur_conv<<<grid, 256, 0, stream>>>(x, ws, out);
    }
}

// Round 7
// 227.537 us; speedup vs baseline: 1.3050x; 1.3050x over previous
//
#include <hip/hip_runtime.h>
#include <math.h>

namespace {

constexpr int Himg = 224, Wimg = 224, Cn = 3, Kk = 32;
constexpr int MAXT = 64;
constexpr int WSTRIDE = 512;               // ints per image in tap workspace
constexpr int IMG_F  = Himg * Wimg * Cn;   // 150528 floats per image
constexpr int ROW_F  = Wimg * Cn;          // 672 floats per row (== 0 mod 4)
constexpr int ROW_B  = ROW_F * 4;          // 2688 B

constexpr int IN_CH  = 144;                // interior chunk-cols: k in [12,156)
constexpr int ED_CH  = 24;                 // edge chunk-cols: k<12 or k>=156
constexpr int IN_PER_IMG = Himg * IN_CH;   // 32256
constexpr int ED_PER_IMG = Himg * ED_CH;   // 5376
constexpr int IN_BLK = IN_PER_IMG / 256;   // 126
constexpr int ED_BLK = ED_PER_IMG / 256;   // 21
constexpr int BLK_PER_IMG = IN_BLK + ED_BLK;  // 147
// interior blocks c in [9,117) have all rows y in [16,208) -> no vertical mask
constexpr int FAST_LO = 9, FAST_HI = 117;

typedef float v4  __attribute__((ext_vector_type(4), aligned(4)));
typedef float v4a __attribute__((ext_vector_type(4), aligned(16)));

// ws per-image layout (ints): [0]=n  [1]=w  [2..65]=dky  [66..129]=dkx  [130..193]=xoff(bytes)

// ---------------- pre-pass: one tap list per image ----------------
__global__ __launch_bounds__(64)
void build_taps(const float* __restrict__ tbl,
                const int* __restrict__ amt,
                const int* __restrict__ ang,
                int* __restrict__ ws)
{
    const int b   = blockIdx.x;
    const int tid = threadIdx.x;

    __shared__ int   s_cnt;
    __shared__ float s_w;
    __shared__ int   s_dky[MAXT], s_dkx[MAXT];

    if (tid == 0) { s_cnt = 0; s_w = 0.0f; }
    __syncthreads();

    const int a = amt[b];
    // reference-exact numerics (verified absmax 0.0039 in R1-R5)
    const float  rad = (float)ang[b] * (float)(M_PI / 180.0);
    const double rd  = (double)rad;
    const float  cth = (float)cos(rd);
    const float  sth = (float)sin(rd);
    const float  e   = 31.0f;
    const float xoff = __fmul_rn(__fsub_rn(e, __fsub_rn(__fmul_rn(cth, e), __fmul_rn(sth, e))), 0.5f);
    const float yoff = __fmul_rn(__fsub_rn(e, __fadd_rn(__fmul_rn(sth, e), __fmul_rn(cth, e))), 0.5f);

    for (int p = tid; p < Kk * Kk; p += 64) {
        const int   ky = p >> 5, kx = p & 31;
        const float xf = (float)kx, yf = (float)ky;
        const float sx = __fadd_rn(__fsub_rn(__fmul_rn(cth, xf), __fmul_rn(sth, yf)), xoff);
        const float sy = __fadd_rn(__fadd_rn(__fmul_rn(sth, xf), __fmul_rn(cth, yf)), yoff);
        const int ix = (int)rintf(sx);   // round-half-even == jnp.round
        const int iy = (int)rintf(sy);
        if (ix >= 0 && ix < Kk && iy >= 0 && iy < Kk) {
            const float v = tbl[((a * Kk + iy) * Kk + ix) * Cn];
            if (v != 0.0f) {
                const int idx = atomicAdd(&s_cnt, 1);
                if (idx < MAXT) {
                    s_dky[idx] = ky - 15;
                    s_dkx[idx] = kx - 15;
                    s_w = v;                 // benign race: all writers store 1/size
                }
            }
        }
    }
    __syncthreads();

    const int n = min(s_cnt, MAXT);
    int* wsb = ws + b * WSTRIDE;
    if (tid == 0) { wsb[0] = n; wsb[1] = __float_as_int(s_w); }
    for (int i = tid; i < n; i += 64) {
        wsb[2 + i]   = s_dky[i];
        wsb[66 + i]  = s_dkx[i];
        wsb[130 + i] = s_dky[i] * ROW_B + s_dkx[i] * (int)(Cn * sizeof(float));
    }
}

// ---------------- conv directly from x, flat-space contiguous loads ----------------
__global__ __launch_bounds__(256)
void blur_direct(const float* __restrict__ x,
                 const int* __restrict__ ws,
                 float* __restrict__ out,
                 int B)
{
    const int tid = threadIdx.x;
    const int L   = blockIdx.x;

    // XCD-pinned decode: image b handled entirely by XCD (b & 7), blocks of an
    // image adjacent in dispatch order (heuristic: linear id -> XCD round-robin).
    int b, c;
    if (B == 128) {
        const int xcd = L & 7;
        const int j   = L >> 3;                 // [0, 16*147)
        const int g   = j / BLK_PER_IMG;        // image group on this XCD
        c = j - g * BLK_PER_IMG;
        b = g * 8 + xcd;
    } else {
        b = L / BLK_PER_IMG;
        c = L - b * BLK_PER_IMG;
    }

    __shared__ int shNW[2];
    __shared__ int s_dky[MAXT], s_dkx[MAXT], s_xoff[MAXT];
    const int* wsb = ws + b * WSTRIDE;
    if (tid < 2)    shNW[tid]   = wsb[tid];
    if (tid < MAXT) {
        s_dky[tid]  = wsb[2 + tid];
        s_dkx[tid]  = wsb[66 + tid];
        s_xoff[tid] = wsb[130 + tid];
    }
    __syncthreads();

    const int   n = shNW[0];
    const float w = __int_as_float(shNW[1]);
    const float* xb = x + (size_t)b * IMG_F;

    if (c < IN_BLK) {
        // ---- interior chunk-columns: contiguous dwordx4 per tap ----
        const int ii = c * 256 + tid;
        const int y  = ii / IN_CH;
        const int k  = ii - y * IN_CH + 12;     // [12, 156)
        const int fbase = y * ROW_F + 4 * k;
        const char* base = (const char*)xb + (size_t)fbase * 4;

        float a0 = 0.0f, a1 = 0.0f, a2 = 0.0f, a3 = 0.0f;

        if (c >= FAST_LO && c < FAST_HI) {
            // fast path: all taps in-bounds, unroll 4 (4 loads in flight)
            int i = 0;
            for (; i + 4 <= n; i += 4) {
                const v4 f0 = *(const v4*)(base + s_xoff[i]);
                const v4 f1 = *(const v4*)(base + s_xoff[i + 1]);
                const v4 f2 = *(const v4*)(base + s_xoff[i + 2]);
                const v4 f3 = *(const v4*)(base + s_xoff[i + 3]);
                a0 += f0.x; a1 += f0.y; a2 += f0.z; a3 += f0.w;
                a0 += f1.x; a1 += f1.y; a2 += f1.z; a3 += f1.w;
                a0 += f2.x; a1 += f2.y; a2 += f2.z; a3 += f2.w;
                a0 += f3.x; a1 += f3.y; a2 += f3.z; a3 += f3.w;
            }
            for (; i < n; ++i) {
                const v4 f = *(const v4*)(base + s_xoff[i]);
                a0 += f.x; a1 += f.y; a2 += f.z; a3 += f.w;
            }
        } else {
            // y-edge blocks: per-lane row mask, branchless, still vector loads
            for (int i = 0; i < n; ++i) {
                const int  row = y + s_dky[i];
                const bool ok  = (unsigned)row < (unsigned)Himg;
                const int  off = ok ? s_xoff[i] : 0;      // base+0 = own chunk (in-bounds)
                const float m  = ok ? 1.0f : 0.0f;
                const v4 f = *(const v4*)(base + off);
                a0 += m * f.x; a1 += m * f.y; a2 += m * f.z; a3 += m * f.w;
            }
        }

        float* o = out + (size_t)b * IMG_F + fbase;
        __builtin_nontemporal_store(v4a{a0 * w, a1 * w, a2 * w, a3 * w}, (v4a*)o);
    } else {
        // ---- x-edge chunk-columns: 4 masked scalar loads per tap ----
        const int ee = (c - IN_BLK) * 256 + tid;
        const int y  = ee / ED_CH;
        const int j  = ee - y * ED_CH;
        const int k  = (j < 12) ? j : (j + 144);   // [0,12) U [156,168)  -- FIXED (was +132)
        const int fd0 = 4 * k;

        float acc[4] = {0.0f, 0.0f, 0.0f, 0.0f};
        for (int i = 0; i < n; ++i) {
            const int  row = y + s_dky[i];
            const bool rok = (unsigned)row < (unsigned)Himg;
            const int  s0  = fd0 + 3 * s_dkx[i];
            const int  ob  = row * ROW_F + s0;
#pragma unroll
            for (int q = 0; q < 4; ++q) {
                const bool ok  = rok & ((unsigned)(s0 + q) < (unsigned)ROW_F);
                const int  off = ok ? (ob + q) : 0;
                const float v  = xb[off];
                acc[q] += ok ? v : 0.0f;
            }
        }

        float* o = out + (size_t)b * IMG_F + (size_t)y * ROW_F + fd0;
        __builtin_nontemporal_store(
            v4a{acc[0] * w, acc[1] * w, acc[2] * w, acc[3] * w}, (v4a*)o);
    }
}

}  // namespace

extern "C" void kernel_launch(void* const* d_in, const int* in_sizes, int n_in,
                              void* d_out, int out_size, void* d_ws, size_t ws_size,
                              hipStream_t stream) {
    const float* x   = (const float*)d_in[0];
    const float* tbl = (const float*)d_in[1];
    const int*   amt = (const int*)d_in[2];
    const int*   ang = (const int*)d_in[3];
    float*       out = (float*)d_out;
    int*         ws  = (int*)d_ws;

    const int B = in_sizes[2];  // 128

    build_taps<<<B, 64, 0, stream>>>(tbl, amt, ang, ws);
    blur_direct<<<B * BLK_PER_IMG, 256, 0, stream>>>(x, ws, out, B);
}